// Round 5
// baseline (254.300 us; speedup 1.0000x reference)
//
#include <hip/hip_runtime.h>

// LabelLoss: out[b] = sum_{n,c<7} (pred[b,n,c] - gt[b,n,c])^2
// pred/gt: [256, 16384, 8] fp32.
//
// History:
//  R1-R4: ~100 us (2.7 TB/s) allocating loads, structure-invariant (TCP
//         cap gated everything in that regime).
//  R6-R7: nt vector loads (L1 bypass) + dbuf pipeline -> ~75 us (3.6 TB/s).
//  R8:    inline-asm VGPR-dest loads w/ manual vmcnt -> core dump. Never
//         hand-roll untracked VGPR-destination loads.
//  R9:    buffer_load sc0 sc1 nt (L1+L2 bypass) -> NULL. Not L2 policy.
//  R10:   LDS-DMA path -> NULL. Not the VGPR-return path.
//  R11:   vector-nt + LDS-DMA CONCURRENT -> NULL. Not a per-path CU cap.
//         => cap lives upstream (fabric/HBM). Reads 3.6 TB/s vs writes 6.9.
//  R12 (this): last unswept axis: ADDRESS-STREAM TOPOLOGY. 2048 blocks x
//         2 tensors = 4096 interleaved read streams ~ HBM bank count ->
//         row-buffer thrash (reads can't be reordered like posted writes;
//         explains read/write asymmetry). Change: SPLIT=1, 256 blocks
//         (1/CU) x 1024 threads, each block = one contiguous 512 KB slab
//         per tensor. 512 chip-wide streams, 64 KB contiguous bursts.
//         Same proven dbuf-nt pipeline. Single writer per out[b] -> plain
//         store, no memset/atomic.
//         If null -> declare structural read roofline (~75 us kernel).

#define THREADS 1024
#define F4_PER_BATCH (16384 * 2)              // 32768 float4s per batch per input
#define DEPTH 4                               // float4s per thread per chunk
#define CHUNK (THREADS * DEPTH)               // 4096 float4s (64 KB) per chunk
#define NCHUNK (F4_PER_BATCH / CHUNK)         // 8 chunks per block (even)

typedef float vfloat4 __attribute__((ext_vector_type(4)));

__global__ __launch_bounds__(THREADS) void label_loss_kernel(
    const vfloat4* __restrict__ pred,
    const vfloat4* __restrict__ gt,
    float* __restrict__ out)
{
    const int tid = (int)threadIdx.x;
    const int b   = blockIdx.x;               // one block per batch row
    const int base_f4 = b * F4_PER_BATCH + tid;

    // Channel-7 mask: float4 index parity == tid&1 (all strides even):
    // lane-uniform, no divergence. Even float4 = ch0-3 (m=1), odd = ch4-7
    // (mask .w = ch7, m=0).
    const float m = (tid & 1) ? 0.0f : 1.0f;

    vfloat4 Pa[DEPTH], Ga[DEPTH], Pb[DEPTH], Gb[DEPTH];
    float acc[DEPTH] = {0.0f, 0.0f, 0.0f, 0.0f};

#define LOAD(P_, G_, c) do {                                              \
    const int o_ = base_f4 + (c) * CHUNK;                                 \
    _Pragma("unroll")                                                     \
    for (int k = 0; k < DEPTH; ++k)                                       \
      P_[k] = __builtin_nontemporal_load(&pred[o_ + k * THREADS]);        \
    _Pragma("unroll")                                                     \
    for (int k = 0; k < DEPTH; ++k)                                       \
      G_[k] = __builtin_nontemporal_load(&gt[o_ + k * THREADS]);          \
  } while (0)

#define CONSUME(P_, G_) do {                                              \
    _Pragma("unroll")                                                     \
    for (int k = 0; k < DEPTH; ++k) {                                     \
      const vfloat4 d_ = P_[k] - G_[k];                                   \
      acc[k] += d_.x * d_.x + d_.y * d_.y + d_.z * d_.z + m * (d_.w * d_.w); \
    }                                                                     \
  } while (0)

    // Prologue: chunk 0 in flight (8 nt loads).
    LOAD(Pa, Ga, 0);

    // Steady state: always >= one chunk (8 loads) outstanding; compiler
    // inserts counted vmcnt (tracked loads).
    #pragma unroll 1
    for (int c = 0; c + 2 < NCHUNK; c += 2) {
        LOAD(Pb, Gb, c + 1);
        CONSUME(Pa, Ga);
        LOAD(Pa, Ga, c + 2);
        CONSUME(Pb, Gb);
    }
    // Epilogue: Pa holds chunk NCHUNK-2 (NCHUNK even).
    LOAD(Pb, Gb, NCHUNK - 1);
    CONSUME(Pa, Ga);
    CONSUME(Pb, Gb);

#undef LOAD
#undef CONSUME

    float v = (acc[0] + acc[1]) + (acc[2] + acc[3]);

    // 64-lane wave reduction
    #pragma unroll
    for (int off = 32; off > 0; off >>= 1)
        v += __shfl_down(v, off, 64);

    __shared__ float wsum[THREADS / 64];
    const int lane = tid & 63;
    const int wave = tid >> 6;
    if (lane == 0) wsum[wave] = v;
    __syncthreads();

    // Single block owns out[b]: plain store, no memset/atomic needed.
    if (tid == 0) {
        float s = 0.0f;
        #pragma unroll
        for (int w = 0; w < THREADS / 64; ++w) s += wsum[w];
        out[b] = s;
    }
}

extern "C" void kernel_launch(void* const* d_in, const int* in_sizes, int n_in,
                              void* d_out, int out_size, void* d_ws, size_t ws_size,
                              hipStream_t stream) {
    const vfloat4* pred = (const vfloat4*)d_in[0];
    const vfloat4* gt   = (const vfloat4*)d_in[1];
    float* out = (float*)d_out;

    label_loss_kernel<<<dim3(256), dim3(THREADS), 0, stream>>>(pred, gt, out);
}